// Round 3
// baseline (441.118 us; speedup 1.0000x reference)
//
#include <hip/hip_runtime.h>
#include <type_traits>

#define DIMC 512
#define NTOK 4097
#define GH 64
#define GW 64
#define TH 16   // output rows per thread (7-slot accumulator ring)
#define WT 4    // output cols per thread (horizontal halo amortization)

// Compile-time-for: guarantees every loop index is a template constant, so
// acc/row/wgt subscripts are static and SROA MUST promote them to registers.
// (Round-2 evidence: #pragma unroll on the 22-iter outer loop was not honored
// — VGPR stayed 64, acc ring lived in scratch, WRITE_SIZE showed +51 MB of
// spill traffic. Rule: runtime-indexed arrays go to scratch.)
template <int I, int N, typename F>
__device__ __forceinline__ void static_for(F&& f)
{
    if constexpr (I < N) {
        f(std::integral_constant<int, I>{});
        static_for<I + 1, N>(f);
    }
}

// Fold w7 + padded(w5) + padded(w3) + identity into one 7x7 depthwise kernel,
// stored tap-major [t][c] so lanes (channels) read coalesced. Bias = b7+b5+b3.
__global__ __launch_bounds__(256) void prep_kernel(
    const float* __restrict__ w7, const float* __restrict__ b7,
    const float* __restrict__ w5, const float* __restrict__ b5,
    const float* __restrict__ w3, const float* __restrict__ b3,
    float* __restrict__ wc, float* __restrict__ bc)
{
    int idx = blockIdx.x * 256 + threadIdx.x;   // 0 .. 512*49-1
    if (idx < DIMC * 49) {
        int c = idx & (DIMC - 1);
        int t = idx >> 9;
        int dy = t / 7, dx = t - dy * 7;
        float v = w7[c * 49 + t];
        if (dy >= 1 && dy <= 5 && dx >= 1 && dx <= 5)
            v += w5[c * 25 + (dy - 1) * 5 + (dx - 1)];
        if (dy >= 2 && dy <= 4 && dx >= 2 && dx <= 4)
            v += w3[c * 9 + (dy - 2) * 3 + (dx - 2)];
        if (dy == 3 && dx == 3) v += 1.0f;      // identity (residual) term
        wc[t * DIMC + c] = v;
    }
    if (idx < DIMC) bc[idx] = b7[idx] + b5[idx] + b3[idx];
}

// cls token pass-through: out[b,0,:] = x[b,0,:]
__global__ __launch_bounds__(256) void cls_kernel(
    const float* __restrict__ x, float* __restrict__ out)
{
    int i = blockIdx.x * 256 + threadIdx.x;     // 0 .. 16*512-1
    int b = i >> 9, c = i & 511;
    size_t off = (size_t)b * NTOK * DIMC + c;
    out[off] = x[off];
}

// Depthwise combined 7x7 conv, channels on lanes, output-stationary streaming.
// Each thread owns a TH x WT output tile of one channel. Input rows stream
// through a 10-wide register row; a 7-row accumulator ring receives scattered
// contributions. All structural loops are static_for -> all array indices are
// compile-time -> fully register-resident (~105 VGPRs: 49 wgt + 28 acc + 10
// row + addressing). waves_per_eu(4,4) holds the 128-VGPR budget.
__global__ __launch_bounds__(256)
__attribute__((amdgpu_waves_per_eu(4, 4)))
void dwconv_kernel(
    const float* __restrict__ x, const float* __restrict__ wc,
    const float* __restrict__ bc, float* __restrict__ out)
{
    const int lane  = threadIdx.x;                   // 0..63 (lane = channel)
    const int wtile = threadIdx.y;                   // 0..3 (wave-uniform)
    const int b     = blockIdx.z;                    // 0..15
    const int cg    = blockIdx.y >> 2;               // channel group 0..7
    const int h0    = (blockIdx.y & 3) * TH;         // output row base
    const int w0    = (blockIdx.x * 4 + wtile) * WT; // output col base (wave-uniform)
    const int cc    = (cg << 6) + lane;              // channel 0..511

    float wgt[49];
    static_for<0, 49>([&](auto tC) {
        constexpr int t = decltype(tC)::value;
        wgt[t] = wc[t * DIMC + cc];
    });
    const float bias = bc[cc];

    const float* __restrict__ xin = x   + ((size_t)b * NTOK + 1) * DIMC + cc;
    float* __restrict__ op        = out + ((size_t)b * NTOK + 1) * DIMC + cc;

    float acc[7][WT];     // accumulator ring: slot k%7 holds output row h0+k
    float row[WT + 6];    // current input row, cols w0-3 .. w0+WT+2

    static_for<0, TH + 6>([&](auto iC) {
        constexpr int i = decltype(iC)::value;       // input row r = h0-3+i
        const int r = h0 + (i - 3);

        // --- load one input row (10 coalesced 256B/wave loads) ---
        if (r >= 0 && r < GH) {                      // wave-uniform guard
            const float* __restrict__ rp = xin + (size_t)r * (GW * DIMC);
            static_for<0, WT + 6>([&](auto jC) {
                constexpr int j = decltype(jC)::value;
                const int col = w0 - 3 + j;          // wave-uniform guard
                row[j] = (col >= 0 && col < GW) ? rp[(size_t)col * DIMC] : 0.0f;
            });
        } else {
            static_for<0, WT + 6>([&](auto jC) {
                constexpr int j = decltype(jC)::value;
                row[j] = 0.0f;
            });
        }

        // --- scatter this row into the <=7 open output rows ---
        // output row k = i - dy uses weight row dy; all compile-time.
        static_for<0, 7>([&](auto dyC) {
            constexpr int dy = decltype(dyC)::value;
            constexpr int k  = i - dy;
            if constexpr (k >= 0 && k < TH) {
                constexpr int s = k % 7;
                static_for<0, WT>([&](auto tC) {
                    constexpr int t = decltype(tC)::value;
                    float a = (dy == 0) ? bias : acc[s][t];
#pragma unroll
                    for (int dx = 0; dx < 7; ++dx)
                        a = fmaf(wgt[dy * 7 + dx], row[t + dx], a);
                    acc[s][t] = a;
                });
            }
        });

        // --- output row k = i-6 just received its last contribution ---
        if constexpr (i >= 6) {
            constexpr int k = i - 6;
            constexpr int s = k % 7;
            static_for<0, WT>([&](auto tC) {
                constexpr int t = decltype(tC)::value;
                op[((size_t)(h0 + k) * GW + (w0 + t)) * DIMC] = acc[s][t];
            });
        }
    });
}

extern "C" void kernel_launch(void* const* d_in, const int* in_sizes, int n_in,
                              void* d_out, int out_size, void* d_ws, size_t ws_size,
                              hipStream_t stream)
{
    const float* x  = (const float*)d_in[0];
    const float* w7 = (const float*)d_in[1];
    const float* b7 = (const float*)d_in[2];
    const float* w5 = (const float*)d_in[3];
    const float* b5 = (const float*)d_in[4];
    const float* w3 = (const float*)d_in[5];
    const float* b3 = (const float*)d_in[6];
    float* out = (float*)d_out;
    float* wcomb = (float*)d_ws;            // 49*512 floats
    float* bcomb = wcomb + 49 * DIMC;       // 512 floats

    prep_kernel<<<98, 256, 0, stream>>>(w7, b7, w5, b5, w3, b3, wcomb, bcomb);
    cls_kernel<<<32, 256, 0, stream>>>(x, out);

    // 4 col-tiles/block x (8 cgroups x 4 row-tiles) x batch; block = 64 lanes x 4 waves
    dim3 grid(4, 32, 16);
    dim3 block(64, 4, 1);
    dwconv_kernel<<<grid, block, 0, stream>>>(x, wcomb, bcomb, out);
}

// Round 4
// 296.896 us; speedup vs baseline: 1.4858x; 1.4858x over previous
//
#include <hip/hip_runtime.h>
#include <type_traits>

#define DIMC 512
#define NTOK 4097
#define GH 64
#define GW 64
#define TH 4    // output rows per thread (acc strip — no ring, no big window)
#define WT 4    // output cols per thread

// Compile-time-for: every array index is a template constant -> SROA promotes.
template <int I, int N, typename F>
__device__ __forceinline__ void static_for(F&& f)
{
    if constexpr (I < N) {
        f(std::integral_constant<int, I>{});
        static_for<I + 1, N>(f);
    }
}

// Fold w7 + padded(w5) + padded(w3) + identity into one 7x7 depthwise kernel,
// stored tap-major [t][c] so lanes (channels) read coalesced. Bias = b7+b5+b3.
__global__ __launch_bounds__(256) void prep_kernel(
    const float* __restrict__ w7, const float* __restrict__ b7,
    const float* __restrict__ w5, const float* __restrict__ b5,
    const float* __restrict__ w3, const float* __restrict__ b3,
    float* __restrict__ wc, float* __restrict__ bc)
{
    int idx = blockIdx.x * 256 + threadIdx.x;   // 0 .. 512*49-1
    if (idx < DIMC * 49) {
        int c = idx & (DIMC - 1);
        int t = idx >> 9;
        int dy = t / 7, dx = t - dy * 7;
        float v = w7[c * 49 + t];
        if (dy >= 1 && dy <= 5 && dx >= 1 && dx <= 5)
            v += w5[c * 25 + (dy - 1) * 5 + (dx - 1)];
        if (dy >= 2 && dy <= 4 && dx >= 2 && dx <= 4)
            v += w3[c * 9 + (dy - 2) * 3 + (dx - 2)];
        if (dy == 3 && dx == 3) v += 1.0f;      // identity (residual) term
        wc[t * DIMC + c] = v;
    }
    if (idx < DIMC) bc[idx] = b7[idx] + b5[idx] + b3[idx];
}

// cls token pass-through: out[b,0,:] = x[b,0,:]
__global__ __launch_bounds__(256) void cls_kernel(
    const float* __restrict__ x, float* __restrict__ out)
{
    int i = blockIdx.x * 256 + threadIdx.x;     // 0 .. 16*512-1
    int b = i >> 9, c = i & 511;
    size_t off = (size_t)b * NTOK * DIMC + c;
    out[off] = x[off];
}

// Depthwise combined 7x7 conv, channels on lanes.
// DESIGNED FOR <=64 VGPRs (rounds 1-3 proved this compiler will not allocate
// more for this kernel; anything bigger spills or remats):
//   - weights live in LDS ([tap][64ch], lane-contiguous -> conflict-free
//     ds_read_b32 at base+imm), NOT in 49 registers;
//   - small acc strip TH=4 x WT=4 (16 regs) + transient row[10];
//   - total demand ~45 VGPRs -> 8 waves/SIMD, zero spill, zero remat.
// Per input row: 10 coalesced 256B loads, scatter into <=4 open output rows
// (7 LDS weight reads + 28 FMAs each). 6.25 global loads/output.
__global__ __launch_bounds__(256) void dwconv_kernel(
    const float* __restrict__ x, const float* __restrict__ wc,
    const float* __restrict__ bc, float* __restrict__ out)
{
    __shared__ float wt_lds[49 * 64];

    const int lane  = threadIdx.x;                 // 0..63 (lane = channel)
    const int wtile = threadIdx.y;                 // 0..3 (wave-uniform)
    const int cs    = blockIdx.x;                  // 0..3 col segment (16 cols)
    const int rs    = blockIdx.y & 15;             // row tile (4 rows)
    const int cg    = blockIdx.y >> 4;             // channel group 0..7
    const int b     = blockIdx.z;                  // 0..15
    const int cc    = (cg << 6) + lane;            // channel 0..511
    const int h0    = rs * TH;                     // output row base
    const int w0    = cs * 16 + wtile * WT;        // output col base (wave-uniform)

    // Stage this channel-group's folded weights: wt_lds[t*64 + c_local]
    for (int j = wtile * 64 + lane; j < 49 * 64; j += 256)
        wt_lds[j] = wc[(j >> 6) * DIMC + (cg << 6) + (j & 63)];
    __syncthreads();

    const float bias = bc[cc];
    const float* __restrict__ xin = x   + ((size_t)b * NTOK + 1) * DIMC + cc;
    float* __restrict__ op        = out + ((size_t)b * NTOK + 1) * DIMC + cc;

    float acc[TH][WT];

    static_for<0, TH + 6>([&](auto iC) {
        constexpr int i = decltype(iC)::value;     // input row r = h0-3+i
        const int r = h0 + (i - 3);

        // --- load one input row (10 coalesced 256B/wave loads) ---
        float row[WT + 6];
        if (r >= 0 && r < GH) {                    // wave-uniform guard
            const float* __restrict__ rp = xin + (size_t)r * (GW * DIMC);
            static_for<0, WT + 6>([&](auto jC) {
                constexpr int j = decltype(jC)::value;
                const int col = w0 - 3 + j;        // wave-uniform guard
                row[j] = (col >= 0 && col < GW) ? rp[(size_t)col * DIMC] : 0.0f;
            });
        } else {
            static_for<0, WT + 6>([&](auto jC) {
                row[decltype(jC)::value] = 0.0f;
            });
        }

        // --- scatter into the <=TH open output rows: k = i - dy ---
        static_for<0, 7>([&](auto dyC) {
            constexpr int dy = decltype(dyC)::value;
            constexpr int k  = i - dy;
            if constexpr (k >= 0 && k < TH) {
                float wr[7];                       // weight row dy from LDS
                static_for<0, 7>([&](auto dxC) {
                    constexpr int dx = decltype(dxC)::value;
                    wr[dx] = wt_lds[(dy * 7 + dx) * 64 + lane];
                });
                static_for<0, WT>([&](auto tC) {
                    constexpr int t = decltype(tC)::value;
                    float a = (dy == 0) ? bias : acc[k][t];
#pragma unroll
                    for (int dx = 0; dx < 7; ++dx)
                        a = fmaf(wr[dx], row[t + dx], a);
                    acc[k][t] = a;
                });
            }
        });

        // --- output row k = i-6 is complete ---
        if constexpr (i >= 6) {
            constexpr int k = i - 6;
            static_for<0, WT>([&](auto tC) {
                constexpr int t = decltype(tC)::value;
                op[((size_t)(h0 + k) * GW + (w0 + t)) * DIMC] = acc[k][t];
            });
        }
    });
}

extern "C" void kernel_launch(void* const* d_in, const int* in_sizes, int n_in,
                              void* d_out, int out_size, void* d_ws, size_t ws_size,
                              hipStream_t stream)
{
    const float* x  = (const float*)d_in[0];
    const float* w7 = (const float*)d_in[1];
    const float* b7 = (const float*)d_in[2];
    const float* w5 = (const float*)d_in[3];
    const float* b5 = (const float*)d_in[4];
    const float* w3 = (const float*)d_in[5];
    const float* b3 = (const float*)d_in[6];
    float* out = (float*)d_out;
    float* wcomb = (float*)d_ws;            // 49*512 floats
    float* bcomb = wcomb + 49 * DIMC;       // 512 floats

    prep_kernel<<<98, 256, 0, stream>>>(w7, b7, w5, b5, w3, b3, wcomb, bcomb);
    cls_kernel<<<32, 256, 0, stream>>>(x, out);

    // grid: colseg(4) x (rowtile(16) + 16*cgroup(8)) x batch(16) = 8192 blocks
    dim3 grid(4, 128, 16);
    dim3 block(64, 4, 1);
    dwconv_kernel<<<grid, block, 0, stream>>>(x, wcomb, bcomb, out);
}